// Round 1
// baseline (439.487 us; speedup 1.0000x reference)
//
#include <hip/hip_runtime.h>
#include <cstdint>
#include <cstddef>

#define N_ATOM 8192
#define N_EDGE 65536
#define DEG    16
#define DIM    64

__device__ __forceinline__ float sigmoidf_(float z) {
  return 1.0f / (1.0f + __expf(-z));
}
__device__ __forceinline__ float lrelu_(float z) {
  return z > 0.0f ? z : 0.01f * z;
}

// ---------------------------------------------------------------------------
// 1) x[n][d] = embed[fp[n]][d]
__global__ __launch_bounds__(256) void k_embed(const int* __restrict__ fp,
                                               const float* __restrict__ emb,
                                               float* __restrict__ x) {
  int i = blockIdx.x * 256 + threadIdx.x;   // float4 index over N_ATOM*16
  int n = i >> 4, q = i & 15;
  float4 v = reinterpret_cast<const float4*>(emb)[(size_t)fp[n] * 16 + q];
  reinterpret_cast<float4*>(x)[i] = v;
}

// ---------------------------------------------------------------------------
// 2) hs = relu(x @ W + b)   [N_ATOM,64]@[64,64]
__global__ __launch_bounds__(256) void k_hs(const float* __restrict__ x,
                                            const float* __restrict__ W,
                                            const float* __restrict__ b,
                                            float* __restrict__ hs) {
  __shared__ float xs[16][68];   // padded: lanes differ in r -> no bank conflict
  __shared__ float Ws[64][64];
  int t = threadIdx.x;
  int r = t >> 4, dq = t & 15, d0 = dq * 4;
  int row = blockIdx.x * 16 + r;
  *reinterpret_cast<float4*>(&xs[r][d0]) =
      reinterpret_cast<const float4*>(x)[(size_t)row * 16 + dq];
#pragma unroll
  for (int q = 0; q < 4; ++q) {
    int p = t + q * 256;
    reinterpret_cast<float4*>(&Ws[0][0])[p] = reinterpret_cast<const float4*>(W)[p];
  }
  __syncthreads();
  float4 acc = reinterpret_cast<const float4*>(b)[dq];
#pragma unroll
  for (int k = 0; k < 64; ++k) {
    float xv = xs[r][k];
    float4 wv = *reinterpret_cast<const float4*>(&Ws[k][d0]);
    acc.x = fmaf(xv, wv.x, acc.x);
    acc.y = fmaf(xv, wv.y, acc.y);
    acc.z = fmaf(xv, wv.z, acc.z);
    acc.w = fmaf(xv, wv.w, acc.w);
  }
  acc.x = fmaxf(acc.x, 0.0f); acc.y = fmaxf(acc.y, 0.0f);
  acc.z = fmaxf(acc.z, 0.0f); acc.w = fmaxf(acc.w, 0.0f);
  reinterpret_cast<float4*>(hs)[(size_t)row * 16 + dq] = acc;
}

// ---------------------------------------------------------------------------
// 3) split-K partial of  part[s] += adj[256-row block, j-range] @ hs
//    block 256 thr: 8 rows x 8 dims per thread; BM=256, BK=16
__global__ __launch_bounds__(256) void k_adj(const float* __restrict__ adj,
                                             const float* __restrict__ hs,
                                             float* __restrict__ part,
                                             int jlen) {
  __shared__ float adjT[16][260];   // [j][row], padded
  __shared__ float hsT[16][68];     // [j][d], padded
  const int t = threadIdx.x;
  const int rg = t >> 3, dg = t & 7;
  const int r0 = rg * 8, d0 = dg * 8;
  const int row0 = blockIdx.x * 256;
  const int j0base = blockIdx.y * jlen;
  float acc[8][8];
#pragma unroll
  for (int a = 0; a < 8; ++a)
#pragma unroll
    for (int bq = 0; bq < 8; ++bq) acc[a][bq] = 0.0f;

  const int ntile = jlen >> 4;
  for (int jt = 0; jt < ntile; ++jt) {
    const int j0 = j0base + jt * 16;
    // stage adjacency tile (256 rows x 16 cols), transposed into LDS
#pragma unroll
    for (int q = 0; q < 4; ++q) {
      int p = t + q * 256;          // 0..1023 float4 slots
      int r = p >> 2;
      int c = (p & 3) * 4;
      float4 v = *reinterpret_cast<const float4*>(
          adj + (size_t)(row0 + r) * N_ATOM + j0 + c);
      adjT[c + 0][r] = v.x;
      adjT[c + 1][r] = v.y;
      adjT[c + 2][r] = v.z;
      adjT[c + 3][r] = v.w;
    }
    {
      int jr = t >> 4, dq = t & 15;
      *reinterpret_cast<float4*>(&hsT[jr][dq * 4]) =
          *reinterpret_cast<const float4*>(hs + (size_t)(j0 + jr) * DIM + dq * 4);
    }
    __syncthreads();
#pragma unroll
    for (int jj = 0; jj < 16; ++jj) {
      float4 a0 = *reinterpret_cast<const float4*>(&adjT[jj][r0]);
      float4 a1 = *reinterpret_cast<const float4*>(&adjT[jj][r0 + 4]);
      float4 h0 = *reinterpret_cast<const float4*>(&hsT[jj][d0]);
      float4 h1 = *reinterpret_cast<const float4*>(&hsT[jj][d0 + 4]);
      float av[8] = {a0.x, a0.y, a0.z, a0.w, a1.x, a1.y, a1.z, a1.w};
      float hv[8] = {h0.x, h0.y, h0.z, h0.w, h1.x, h1.y, h1.z, h1.w};
#pragma unroll
      for (int a = 0; a < 8; ++a)
#pragma unroll
        for (int bq = 0; bq < 8; ++bq)
          acc[a][bq] = fmaf(av[a], hv[bq], acc[a][bq]);
    }
    __syncthreads();
  }
  float* pp = part + (size_t)blockIdx.y * N_ATOM * DIM;
#pragma unroll
  for (int a = 0; a < 8; ++a) {
    size_t base = (size_t)(row0 + r0 + a) * DIM + d0;
    *reinterpret_cast<float4*>(pp + base) =
        make_float4(acc[a][0], acc[a][1], acc[a][2], acc[a][3]);
    *reinterpret_cast<float4*>(pp + base + 4) =
        make_float4(acc[a][4], acc[a][5], acc[a][6], acc[a][7]);
  }
}

// 4) x += sum_s part[s]
__global__ __launch_bounds__(256) void k_adj_red(float* __restrict__ x,
                                                 const float* __restrict__ part,
                                                 int S) {
  int i = blockIdx.x * 256 + threadIdx.x;    // float4 idx over N_ATOM*16
  float4 v = reinterpret_cast<float4*>(x)[i];
  for (int s = 0; s < S; ++s) {
    float4 p = reinterpret_cast<const float4*>(part)[(size_t)s * (N_ATOM * 16) + i];
    v.x += p.x; v.y += p.y; v.z += p.z; v.w += p.w;
  }
  reinterpret_cast<float4*>(x)[i] = v;
}

// ---------------------------------------------------------------------------
// 5) bond_f = bond_feature @ bond_W + bond_b    [E,10]@[10,64]
__global__ __launch_bounds__(256) void k_bondf(const float* __restrict__ bf,
                                               const float* __restrict__ W,
                                               const float* __restrict__ b,
                                               float* __restrict__ out) {
  int t = threadIdx.x;
  int r = t >> 4, dq = t & 15;
  int row = blockIdx.x * 16 + r;
  float4 acc = reinterpret_cast<const float4*>(b)[dq];
  const float* br = bf + (size_t)row * 10;
#pragma unroll
  for (int k = 0; k < 10; ++k) {
    float xv = br[k];
    float4 wv = reinterpret_cast<const float4*>(W)[k * 16 + dq];
    acc.x = fmaf(xv, wv.x, acc.x);
    acc.y = fmaf(xv, wv.y, acc.y);
    acc.z = fmaf(xv, wv.z, acc.z);
    acc.w = fmaf(xv, wv.w, acc.w);
  }
  reinterpret_cast<float4*>(out)[(size_t)row * 16 + dq] = acc;
}

// ---------------------------------------------------------------------------
// 6) merged pre-GEMMs: A = atom_f @ W_an + neigh_b   (blocks [0,512))
//                      B = bond_f @ W_bn             (blocks [512,4608))
__global__ __launch_bounds__(256) void k_AB(const float* __restrict__ atom_f,
                                            const float* __restrict__ bond_f,
                                            const float* __restrict__ nWi,
                                            const float* __restrict__ nbi,
                                            float* __restrict__ A,
                                            float* __restrict__ B) {
  __shared__ float xs[16][68];
  __shared__ float Ws[64][64];
  int t = threadIdx.x;
  int r = t >> 4, dq = t & 15, d0 = dq * 4;
  bool isA = blockIdx.x < (N_ATOM / 16);
  const float* in; const float* W; float* out; int row;
  if (isA) { in = atom_f; W = nWi;           out = A; row = blockIdx.x * 16 + r; }
  else     { in = bond_f; W = nWi + 64 * 64; out = B; row = (blockIdx.x - N_ATOM / 16) * 16 + r; }
  *reinterpret_cast<float4*>(&xs[r][d0]) =
      reinterpret_cast<const float4*>(in)[(size_t)row * 16 + dq];
#pragma unroll
  for (int q = 0; q < 4; ++q) {
    int p = t + q * 256;
    reinterpret_cast<float4*>(&Ws[0][0])[p] = reinterpret_cast<const float4*>(W)[p];
  }
  __syncthreads();
  float4 acc = make_float4(0.f, 0.f, 0.f, 0.f);
  if (isA) acc = reinterpret_cast<const float4*>(nbi)[dq];
#pragma unroll
  for (int k = 0; k < 64; ++k) {
    float xv = xs[r][k];
    float4 wv = *reinterpret_cast<const float4*>(&Ws[k][d0]);
    acc.x = fmaf(xv, wv.x, acc.x);
    acc.y = fmaf(xv, wv.y, acc.y);
    acc.z = fmaf(xv, wv.z, acc.z);
    acc.w = fmaf(xv, wv.w, acc.w);
  }
  reinterpret_cast<float4*>(out)[(size_t)row * 16 + dq] = acc;
}

// ---------------------------------------------------------------------------
// 7) atom_f = sigmoid(atom_f + sum_deg lrelu(A[ai] + B[bi]))
__global__ __launch_bounds__(256) void k_upd(const int* __restrict__ adl,
                                             const int* __restrict__ bdl,
                                             const float* __restrict__ A,
                                             const float* __restrict__ B,
                                             float* __restrict__ atom_f) {
  int t = threadIdx.x;
  int r = t >> 4, dq = t & 15;
  int n = blockIdx.x * 16 + r;
  float4 s = make_float4(0.f, 0.f, 0.f, 0.f);
#pragma unroll
  for (int g = 0; g < DEG; ++g) {
    int ai = adl[n * DEG + g];
    int bi = bdl[n * DEG + g];
    float4 va = reinterpret_cast<const float4*>(A)[(size_t)ai * 16 + dq];
    float4 vb = reinterpret_cast<const float4*>(B)[(size_t)bi * 16 + dq];
    s.x += lrelu_(va.x + vb.x);
    s.y += lrelu_(va.y + vb.y);
    s.z += lrelu_(va.z + vb.z);
    s.w += lrelu_(va.w + vb.w);
  }
  float4 af = reinterpret_cast<const float4*>(atom_f)[(size_t)n * 16 + dq];
  af.x = sigmoidf_(af.x + s.x);
  af.y = sigmoidf_(af.y + s.y);
  af.z = sigmoidf_(af.z + s.z);
  af.w = sigmoidf_(af.w + s.w);
  reinterpret_cast<float4*>(atom_f)[(size_t)n * 16 + dq] = af;
}

// ---------------------------------------------------------------------------
// 8) fused: bond_f = sigmoid(bond_f + (af[i0]+af[i1]) @ side_W + side_b)
__global__ __launch_bounds__(256) void k_side(const int* __restrict__ ibj,
                                              const float* __restrict__ atom_f,
                                              const float* __restrict__ sW,
                                              const float* __restrict__ sb,
                                              float* __restrict__ bond_f) {
  __shared__ float ps[16][68];
  __shared__ float Ws[64][64];
  int t = threadIdx.x;
  int r = t >> 4, dq = t & 15, d0 = dq * 4;
  int e = blockIdx.x * 16 + r;
  int i0 = ibj[e * 2], i1 = ibj[e * 2 + 1];
  float4 p0 = reinterpret_cast<const float4*>(atom_f)[(size_t)i0 * 16 + dq];
  float4 p1 = reinterpret_cast<const float4*>(atom_f)[(size_t)i1 * 16 + dq];
  float4 pv = make_float4(p0.x + p1.x, p0.y + p1.y, p0.z + p1.z, p0.w + p1.w);
  *reinterpret_cast<float4*>(&ps[r][d0]) = pv;
#pragma unroll
  for (int q = 0; q < 4; ++q) {
    int p = t + q * 256;
    reinterpret_cast<float4*>(&Ws[0][0])[p] = reinterpret_cast<const float4*>(sW)[p];
  }
  __syncthreads();
  float4 acc = reinterpret_cast<const float4*>(sb)[dq];
#pragma unroll
  for (int k = 0; k < 64; ++k) {
    float xv = ps[r][k];
    float4 wv = *reinterpret_cast<const float4*>(&Ws[k][d0]);
    acc.x = fmaf(xv, wv.x, acc.x);
    acc.y = fmaf(xv, wv.y, acc.y);
    acc.z = fmaf(xv, wv.z, acc.z);
    acc.w = fmaf(xv, wv.w, acc.w);
  }
  float4 bf = reinterpret_cast<const float4*>(bond_f)[(size_t)e * 16 + dq];
  bf.x = sigmoidf_(bf.x + acc.x);
  bf.y = sigmoidf_(bf.y + acc.y);
  bf.z = sigmoidf_(bf.z + acc.z);
  bf.w = sigmoidf_(bf.w + acc.w);
  reinterpret_cast<float4*>(bond_f)[(size_t)e * 16 + dq] = bf;
}

// ---------------------------------------------------------------------------
// 9) partial column sums of (x + atom_f): mp[blk][64]
__global__ __launch_bounds__(256) void k_meanpart(const float* __restrict__ x,
                                                  const float* __restrict__ af,
                                                  float* __restrict__ mp) {
  __shared__ float4 red[256];
  int t = threadIdx.x;
  int rs = t >> 4, dq = t & 15;
  float4 s = make_float4(0.f, 0.f, 0.f, 0.f);
#pragma unroll
  for (int k = 0; k < 8; ++k) {
    int row = blockIdx.x * 128 + k * 16 + rs;
    float4 a = reinterpret_cast<const float4*>(x)[(size_t)row * 16 + dq];
    float4 b = reinterpret_cast<const float4*>(af)[(size_t)row * 16 + dq];
    s.x += a.x + b.x; s.y += a.y + b.y; s.z += a.z + b.z; s.w += a.w + b.w;
  }
  red[t] = s;
  __syncthreads();
  for (int h = 8; h >= 1; h >>= 1) {
    if (rs < h) {
      float4 o = red[t + h * 16];
      s.x += o.x; s.y += o.y; s.z += o.z; s.w += o.w;
      red[t] = s;
    }
    __syncthreads();
  }
  if (rs == 0) reinterpret_cast<float4*>(mp)[blockIdx.x * 16 + dq] = red[t];
}

// ---------------------------------------------------------------------------
// 10) tail: disease mean + miRNA MLP + output layers -> d_out[2]
__global__ __launch_bounds__(256) void k_tail(const float* __restrict__ mp,
                                              const float* __restrict__ words,
                                              const float* __restrict__ fcW,
                                              const float* __restrict__ fcb,
                                              const float* __restrict__ oW,
                                              const float* __restrict__ ob,
                                              const float* __restrict__ iW,
                                              const float* __restrict__ ib,
                                              float* __restrict__ out) {
  __shared__ float cat[128];
  __shared__ float mred[4][64];
  int t = threadIdx.x;
  if (t < 64) {
    float s = 0.f;
    for (int w = 0; w < 64; ++w) s += mp[w * 64 + t];
    cat[t] = s * (1.0f / N_ATOM);
  }
  {
    int ch = t >> 6, d = t & 63;
    float s = 0.f;
    for (int q = 0; q < 256; ++q) {
      int k = ch * 256 + q;
      s = fmaf(words[k], fcW[(size_t)k * 64 + d], s);
    }
    mred[ch][d] = s;
  }
  __syncthreads();
  if (t < 64) cat[64 + t] = mred[0][t] + mred[1][t] + mred[2][t] + mred[3][t] + fcb[t];
  __syncthreads();
  for (int j = 0; j < 2; ++j) {
    float s = 0.f;
    if (t < 128) {
      s = ob[j * 128 + t];
      for (int k = 0; k < 128; ++k)
        s = fmaf(cat[k], oW[(size_t)j * 128 * 128 + k * 128 + t], s);
      s = fmaxf(s, 0.f);
    }
    __syncthreads();
    if (t < 128) cat[t] = s;
    __syncthreads();
  }
  if (t < 2) {
    float s = ib[t];
    for (int k = 0; k < 128; ++k) s = fmaf(cat[k], iW[k * 2 + t], s);
    out[t] = s;
  }
}

// ---------------------------------------------------------------------------
extern "C" void kernel_launch(void* const* d_in, const int* in_sizes, int n_in,
                              void* d_out, int out_size, void* d_ws, size_t ws_size,
                              hipStream_t stream) {
  const int*   fp    = (const int*)  d_in[0];
  const int*   adl   = (const int*)  d_in[1];
  const float* bfeat = (const float*)d_in[2];
  const int*   bdl   = (const int*)  d_in[3];
  const int*   ibj   = (const int*)  d_in[4];
  const float* adj   = (const float*)d_in[5];
  const float* words = (const float*)d_in[6];
  const float* emb   = (const float*)d_in[7];
  const float* bW    = (const float*)d_in[8];
  const float* bb    = (const float*)d_in[9];
  const float* subW  = (const float*)d_in[10];
  const float* subb  = (const float*)d_in[11];
  const float* nW    = (const float*)d_in[12];
  const float* nb    = (const float*)d_in[13];
  const float* sW    = (const float*)d_in[14];
  const float* sb    = (const float*)d_in[15];
  const float* fcW   = (const float*)d_in[16];
  const float* fcb   = (const float*)d_in[17];
  const float* oW    = (const float*)d_in[18];
  const float* ob    = (const float*)d_in[19];
  const float* iW    = (const float*)d_in[20];
  const float* ib    = (const float*)d_in[21];
  float* out = (float*)d_out;

  char* ws = (char*)d_ws;
  const size_t MB = 1ull << 20;
  float* x      = (float*)(ws + 0 * MB);    // 2 MB
  float* hs     = (float*)(ws + 2 * MB);    // 2 MB
  float* atom_f = (float*)(ws + 4 * MB);    // 2 MB
  float* A      = (float*)(ws + 6 * MB);    // 2 MB
  float* bond_f = (float*)(ws + 8 * MB);    // 16 MB
  float* B      = (float*)(ws + 24 * MB);   // 16 MB
  float* part   = (float*)(ws + 40 * MB);   // S * 2 MB

  // pick split-K factor that fits the workspace
  int S = 16;
  while (S > 1 &&
         ws_size < 40 * MB + (size_t)S * (N_ATOM * DIM * 4) + (64ull << 10))
    S >>= 1;
  float* mp = (float*)(ws + 40 * MB + (size_t)S * (N_ATOM * DIM * 4)); // 16 KB

  // sub_graph: x = embed; 2x { hs = relu(x@subW+b); x += adj@hs }
  k_embed<<<512, 256, 0, stream>>>(fp, emb, x);
  for (int i = 0; i < 2; ++i) {
    k_hs<<<512, 256, 0, stream>>>(x, subW + i * 64 * 64, subb + i * 64, hs);
    dim3 g(32, S);
    k_adj<<<g, 256, 0, stream>>>(adj, hs, part, N_ATOM / S);
    k_adj_red<<<512, 256, 0, stream>>>(x, part, S);
  }

  // GNN
  k_bondf<<<N_EDGE / 16, 256, 0, stream>>>(bfeat, bW, bb, bond_f);
  hipMemcpyAsync(atom_f, x, (size_t)N_ATOM * DIM * 4, hipMemcpyDeviceToDevice,
                 stream);
  for (int i = 0; i < 3; ++i) {
    k_AB<<<N_ATOM / 16 + N_EDGE / 16, 256, 0, stream>>>(
        atom_f, bond_f, nW + i * 128 * 64, nb + i * 64, A, B);
    k_upd<<<N_ATOM / 16, 256, 0, stream>>>(adl, bdl, A, B, atom_f);
    k_side<<<N_EDGE / 16, 256, 0, stream>>>(ibj, atom_f, sW + i * 64 * 64,
                                            sb + i * 64, bond_f);
  }

  // tail
  k_meanpart<<<64, 256, 0, stream>>>(x, atom_f, mp);
  k_tail<<<1, 256, 0, stream>>>(mp, words, fcW, fcb, oW, ob, iW, ib, out);
}

// Round 2
// 323.540 us; speedup vs baseline: 1.3584x; 1.3584x over previous
//
#include <hip/hip_runtime.h>
#include <cstdint>
#include <cstddef>

#define N_ATOM 8192
#define N_EDGE 65536
#define DEG    16
#define DIM    64
#define ADJ_S  8      // split-K slices for adjacency GEMM
#define BM     128
#define BK     64

typedef __attribute__((ext_vector_type(8))) short bf16x8_t;
typedef __attribute__((ext_vector_type(4))) float f32x4_t;

__device__ __forceinline__ float sigmoidf_(float z) {
  return 1.0f / (1.0f + __expf(-z));
}
__device__ __forceinline__ float lrelu_(float z) {
  return z > 0.0f ? z : 0.01f * z;
}
__device__ __forceinline__ unsigned short f2bf(float f) {
  union { float f; uint32_t u; } v; v.f = f;
  uint32_t r = v.u + 0x7fff + ((v.u >> 16) & 1);   // RNE
  return (unsigned short)(r >> 16);
}

// ---------------------------------------------------------------------------
// Fused row-local producer + hs GEMM.
// mode 0: x = embed[fp];           hsT = bf16(relu(x@W+b))^T
// mode 1: x += sum_s part[s];      hsT = bf16(relu(x@W+b))^T
// 16 rows / block, 512 blocks.
__global__ __launch_bounds__(256) void k_pre_hs(
    int mode, const int* __restrict__ fp, const float* __restrict__ emb,
    const float* __restrict__ part, float* __restrict__ x,
    const float* __restrict__ W, const float* __restrict__ b,
    unsigned short* __restrict__ hsT /* [DIM][N_ATOM] */) {
  __shared__ float xs[16][68];
  __shared__ float Ws[64][64];
  const int t = threadIdx.x;
  const int r = t >> 4, dq = t & 15, d0 = dq * 4;
  const int row = blockIdx.x * 16 + r;
  float4 v;
  if (mode == 0) {
    v = reinterpret_cast<const float4*>(emb)[(size_t)fp[row] * 16 + dq];
  } else {
    v = reinterpret_cast<const float4*>(x)[(size_t)row * 16 + dq];
#pragma unroll
    for (int s = 0; s < ADJ_S; ++s) {
      float4 p = reinterpret_cast<const float4*>(part)
                     [(size_t)s * (N_ATOM * 16) + (size_t)row * 16 + dq];
      v.x += p.x; v.y += p.y; v.z += p.z; v.w += p.w;
    }
  }
  reinterpret_cast<float4*>(x)[(size_t)row * 16 + dq] = v;
  *reinterpret_cast<float4*>(&xs[r][d0]) = v;
#pragma unroll
  for (int q = 0; q < 4; ++q) {
    int p = t + q * 256;
    reinterpret_cast<float4*>(&Ws[0][0])[p] = reinterpret_cast<const float4*>(W)[p];
  }
  __syncthreads();
  float4 acc = reinterpret_cast<const float4*>(b)[dq];
#pragma unroll
  for (int k = 0; k < 64; ++k) {
    float xv = xs[r][k];
    float4 wv = *reinterpret_cast<const float4*>(&Ws[k][d0]);
    acc.x = fmaf(xv, wv.x, acc.x);
    acc.y = fmaf(xv, wv.y, acc.y);
    acc.z = fmaf(xv, wv.z, acc.z);
    acc.w = fmaf(xv, wv.w, acc.w);
  }
  float a4[4] = {acc.x, acc.y, acc.z, acc.w};
#pragma unroll
  for (int j = 0; j < 4; ++j)
    hsT[(size_t)(d0 + j) * N_ATOM + row] = f2bf(fmaxf(a4[j], 0.0f));
}

// ---------------------------------------------------------------------------
// Split-K bf16-MFMA GEMM: part[s] = adj[block rows, K-slice] @ hs
// adj fp32 streamed + converted inline; hs as bf16^T [DIM][N_ATOM].
// grid (64, ADJ_S), 256 threads (4 waves), BM=128, BK=64.
__global__ __launch_bounds__(256) void k_adjmm(
    const float* __restrict__ adj, const unsigned short* __restrict__ hsT,
    float* __restrict__ part) {
  __shared__ unsigned short Asub[BM][BK + 8];  // 128 x 72 ush (144 B rows)
  __shared__ unsigned short Bsub[64][BK + 8];  // 64 x 72 ush
  const int t = threadIdx.x;
  const int lane = t & 63, w = t >> 6;
  const int row0 = blockIdx.x * BM;
  const int kbase0 = blockIdx.y * (N_ATOM / ADJ_S);
  const int NSTEP = (N_ATOM / ADJ_S) / BK;   // 16

  f32x4_t acc[2][4];
#pragma unroll
  for (int m = 0; m < 2; ++m)
#pragma unroll
    for (int n = 0; n < 4; ++n)
      acc[m][n] = (f32x4_t){0.f, 0.f, 0.f, 0.f};

  float4 ar[4][2];
  bf16x8_t br[2];

#define STAGE_LOAD(KB)                                                        \
  {                                                                           \
    _Pragma("unroll")                                                         \
    for (int i = 0; i < 4; ++i) {                                             \
      int u = i * 256 + t;                                                    \
      int rr = u >> 3, kc = u & 7;                                            \
      const float4* p = reinterpret_cast<const float4*>(                      \
          adj + (size_t)(row0 + rr) * N_ATOM + (KB) + kc * 8);                \
      ar[i][0] = p[0];                                                        \
      ar[i][1] = p[1];                                                        \
    }                                                                         \
    _Pragma("unroll")                                                         \
    for (int i = 0; i < 2; ++i) {                                             \
      int u = i * 256 + t;                                                    \
      int dd = u >> 3, kc = u & 7;                                            \
      br[i] = *reinterpret_cast<const bf16x8_t*>(                             \
          hsT + (size_t)dd * N_ATOM + (KB) + kc * 8);                         \
    }                                                                         \
  }

#define STAGE_WRITE()                                                         \
  {                                                                           \
    _Pragma("unroll")                                                         \
    for (int i = 0; i < 4; ++i) {                                             \
      int u = i * 256 + t;                                                    \
      int rr = u >> 3, kc = u & 7;                                            \
      const float* f0 = reinterpret_cast<const float*>(&ar[i][0]);            \
      bf16x8_t vv;                                                            \
      _Pragma("unroll")                                                       \
      for (int e = 0; e < 8; ++e) vv[e] = (short)f2bf(f0[e]);                 \
      *reinterpret_cast<bf16x8_t*>(&Asub[rr][kc * 8]) = vv;                   \
    }                                                                         \
    _Pragma("unroll")                                                         \
    for (int i = 0; i < 2; ++i) {                                             \
      int u = i * 256 + t;                                                    \
      int dd = u >> 3, kc = u & 7;                                            \
      *reinterpret_cast<bf16x8_t*>(&Bsub[dd][kc * 8]) = br[i];                \
    }                                                                         \
  }

  STAGE_LOAD(kbase0);
  for (int s = 0; s < NSTEP; ++s) {
    __syncthreads();            // LDS consumers of previous step are done
    STAGE_WRITE();
    __syncthreads();
    if (s + 1 < NSTEP) STAGE_LOAD(kbase0 + (s + 1) * BK);
#pragma unroll
    for (int kf = 0; kf < 2; ++kf) {
      const int ko = kf * 32 + (lane >> 4) * 8;
      bf16x8_t a0 = *reinterpret_cast<const bf16x8_t*>(
          &Asub[w * 32 + (lane & 15)][ko]);
      bf16x8_t a1 = *reinterpret_cast<const bf16x8_t*>(
          &Asub[w * 32 + 16 + (lane & 15)][ko]);
      bf16x8_t bb[4];
#pragma unroll
      for (int n = 0; n < 4; ++n)
        bb[n] = *reinterpret_cast<const bf16x8_t*>(
            &Bsub[n * 16 + (lane & 15)][ko]);
#pragma unroll
      for (int n = 0; n < 4; ++n) {
        acc[0][n] = __builtin_amdgcn_mfma_f32_16x16x32_bf16(a0, bb[n], acc[0][n], 0, 0, 0);
        acc[1][n] = __builtin_amdgcn_mfma_f32_16x16x32_bf16(a1, bb[n], acc[1][n], 0, 0, 0);
      }
    }
  }
#undef STAGE_LOAD
#undef STAGE_WRITE

  float* pp = part + (size_t)blockIdx.y * (N_ATOM * DIM);
#pragma unroll
  for (int m = 0; m < 2; ++m)
#pragma unroll
    for (int n = 0; n < 4; ++n)
#pragma unroll
      for (int rg = 0; rg < 4; ++rg) {
        int row = row0 + w * 32 + m * 16 + (lane >> 4) * 4 + rg;
        int col = n * 16 + (lane & 15);
        pp[(size_t)row * DIM + col] = acc[m][n][rg];
      }
}

// ---------------------------------------------------------------------------
// x += sum_s part[s]; atom_f = x
__global__ __launch_bounds__(256) void k_red_final(float* __restrict__ x,
                                                   float* __restrict__ atom_f,
                                                   const float* __restrict__ part) {
  int i = blockIdx.x * 256 + threadIdx.x;   // float4 idx over N_ATOM*16
  float4 v = reinterpret_cast<float4*>(x)[i];
#pragma unroll
  for (int s = 0; s < ADJ_S; ++s) {
    float4 p = reinterpret_cast<const float4*>(part)[(size_t)s * (N_ATOM * 16) + i];
    v.x += p.x; v.y += p.y; v.z += p.z; v.w += p.w;
  }
  reinterpret_cast<float4*>(x)[i] = v;
  reinterpret_cast<float4*>(atom_f)[i] = v;
}

// ---------------------------------------------------------------------------
// bond_f = bond_feature @ bond_W + bond_b    [E,10]@[10,64]
__global__ __launch_bounds__(256) void k_bondf(const float* __restrict__ bf,
                                               const float* __restrict__ W,
                                               const float* __restrict__ b,
                                               float* __restrict__ out) {
  int t = threadIdx.x;
  int r = t >> 4, dq = t & 15;
  int row = blockIdx.x * 16 + r;
  float4 acc = reinterpret_cast<const float4*>(b)[dq];
  const float* br = bf + (size_t)row * 10;
#pragma unroll
  for (int k = 0; k < 10; ++k) {
    float xv = br[k];
    float4 wv = reinterpret_cast<const float4*>(W)[k * 16 + dq];
    acc.x = fmaf(xv, wv.x, acc.x);
    acc.y = fmaf(xv, wv.y, acc.y);
    acc.z = fmaf(xv, wv.z, acc.z);
    acc.w = fmaf(xv, wv.w, acc.w);
  }
  reinterpret_cast<float4*>(out)[(size_t)row * 16 + dq] = acc;
}

// ---------------------------------------------------------------------------
// merged pre-GEMMs: A = atom_f @ W_an + neigh_b ; B = bond_f @ W_bn
__global__ __launch_bounds__(256) void k_AB(const float* __restrict__ atom_f,
                                            const float* __restrict__ bond_f,
                                            const float* __restrict__ nWi,
                                            const float* __restrict__ nbi,
                                            float* __restrict__ A,
                                            float* __restrict__ B) {
  __shared__ float xs[16][68];
  __shared__ float Ws[64][64];
  int t = threadIdx.x;
  int r = t >> 4, dq = t & 15, d0 = dq * 4;
  bool isA = blockIdx.x < (N_ATOM / 16);
  const float* in; const float* W; float* out; int row;
  if (isA) { in = atom_f; W = nWi;           out = A; row = blockIdx.x * 16 + r; }
  else     { in = bond_f; W = nWi + 64 * 64; out = B; row = (blockIdx.x - N_ATOM / 16) * 16 + r; }
  *reinterpret_cast<float4*>(&xs[r][d0]) =
      reinterpret_cast<const float4*>(in)[(size_t)row * 16 + dq];
#pragma unroll
  for (int q = 0; q < 4; ++q) {
    int p = t + q * 256;
    reinterpret_cast<float4*>(&Ws[0][0])[p] = reinterpret_cast<const float4*>(W)[p];
  }
  __syncthreads();
  float4 acc = make_float4(0.f, 0.f, 0.f, 0.f);
  if (isA) acc = reinterpret_cast<const float4*>(nbi)[dq];
#pragma unroll
  for (int k = 0; k < 64; ++k) {
    float xv = xs[r][k];
    float4 wv = *reinterpret_cast<const float4*>(&Ws[k][d0]);
    acc.x = fmaf(xv, wv.x, acc.x);
    acc.y = fmaf(xv, wv.y, acc.y);
    acc.z = fmaf(xv, wv.z, acc.z);
    acc.w = fmaf(xv, wv.w, acc.w);
  }
  reinterpret_cast<float4*>(out)[(size_t)row * 16 + dq] = acc;
}

// ---------------------------------------------------------------------------
// atom_f = sigmoid(atom_f + sum_deg lrelu(A[ai] + B[bi]))
__global__ __launch_bounds__(256) void k_upd(const int* __restrict__ adl,
                                             const int* __restrict__ bdl,
                                             const float* __restrict__ A,
                                             const float* __restrict__ B,
                                             float* __restrict__ atom_f) {
  int t = threadIdx.x;
  int r = t >> 4, dq = t & 15;
  int n = blockIdx.x * 16 + r;
  float4 s = make_float4(0.f, 0.f, 0.f, 0.f);
#pragma unroll
  for (int g = 0; g < DEG; ++g) {
    int ai = adl[n * DEG + g];
    int bi = bdl[n * DEG + g];
    float4 va = reinterpret_cast<const float4*>(A)[(size_t)ai * 16 + dq];
    float4 vb = reinterpret_cast<const float4*>(B)[(size_t)bi * 16 + dq];
    s.x += lrelu_(va.x + vb.x);
    s.y += lrelu_(va.y + vb.y);
    s.z += lrelu_(va.z + vb.z);
    s.w += lrelu_(va.w + vb.w);
  }
  float4 af = reinterpret_cast<const float4*>(atom_f)[(size_t)n * 16 + dq];
  af.x = sigmoidf_(af.x + s.x);
  af.y = sigmoidf_(af.y + s.y);
  af.z = sigmoidf_(af.z + s.z);
  af.w = sigmoidf_(af.w + s.w);
  reinterpret_cast<float4*>(atom_f)[(size_t)n * 16 + dq] = af;
}

// ---------------------------------------------------------------------------
// bond_f = sigmoid(bond_f + (af[i0]+af[i1]) @ side_W + side_b)
__global__ __launch_bounds__(256) void k_side(const int* __restrict__ ibj,
                                              const float* __restrict__ atom_f,
                                              const float* __restrict__ sW,
                                              const float* __restrict__ sb,
                                              float* __restrict__ bond_f) {
  __shared__ float ps[16][68];
  __shared__ float Ws[64][64];
  int t = threadIdx.x;
  int r = t >> 4, dq = t & 15, d0 = dq * 4;
  int e = blockIdx.x * 16 + r;
  int i0 = ibj[e * 2], i1 = ibj[e * 2 + 1];
  float4 p0 = reinterpret_cast<const float4*>(atom_f)[(size_t)i0 * 16 + dq];
  float4 p1 = reinterpret_cast<const float4*>(atom_f)[(size_t)i1 * 16 + dq];
  float4 pv = make_float4(p0.x + p1.x, p0.y + p1.y, p0.z + p1.z, p0.w + p1.w);
  *reinterpret_cast<float4*>(&ps[r][d0]) = pv;
#pragma unroll
  for (int q = 0; q < 4; ++q) {
    int p = t + q * 256;
    reinterpret_cast<float4*>(&Ws[0][0])[p] = reinterpret_cast<const float4*>(sW)[p];
  }
  __syncthreads();
  float4 acc = reinterpret_cast<const float4*>(sb)[dq];
#pragma unroll
  for (int k = 0; k < 64; ++k) {
    float xv = ps[r][k];
    float4 wv = *reinterpret_cast<const float4*>(&Ws[k][d0]);
    acc.x = fmaf(xv, wv.x, acc.x);
    acc.y = fmaf(xv, wv.y, acc.y);
    acc.z = fmaf(xv, wv.z, acc.z);
    acc.w = fmaf(xv, wv.w, acc.w);
  }
  float4 bf = reinterpret_cast<const float4*>(bond_f)[(size_t)e * 16 + dq];
  bf.x = sigmoidf_(bf.x + acc.x);
  bf.y = sigmoidf_(bf.y + acc.y);
  bf.z = sigmoidf_(bf.z + acc.z);
  bf.w = sigmoidf_(bf.w + acc.w);
  reinterpret_cast<float4*>(bond_f)[(size_t)e * 16 + dq] = bf;
}

// ---------------------------------------------------------------------------
// partial column sums of (x + atom_f): mp[blk][64]
__global__ __launch_bounds__(256) void k_meanpart(const float* __restrict__ x,
                                                  const float* __restrict__ af,
                                                  float* __restrict__ mp) {
  __shared__ float4 red[256];
  int t = threadIdx.x;
  int rs = t >> 4, dq = t & 15;
  float4 s = make_float4(0.f, 0.f, 0.f, 0.f);
#pragma unroll
  for (int k = 0; k < 8; ++k) {
    int row = blockIdx.x * 128 + k * 16 + rs;
    float4 a = reinterpret_cast<const float4*>(x)[(size_t)row * 16 + dq];
    float4 b = reinterpret_cast<const float4*>(af)[(size_t)row * 16 + dq];
    s.x += a.x + b.x; s.y += a.y + b.y; s.z += a.z + b.z; s.w += a.w + b.w;
  }
  red[t] = s;
  __syncthreads();
  for (int h = 8; h >= 1; h >>= 1) {
    if (rs < h) {
      float4 o = red[t + h * 16];
      s.x += o.x; s.y += o.y; s.z += o.z; s.w += o.w;
      red[t] = s;
    }
    __syncthreads();
  }
  if (rs == 0) reinterpret_cast<float4*>(mp)[blockIdx.x * 16 + dq] = red[t];
}

// ---------------------------------------------------------------------------
// tail: disease mean + miRNA MLP + output layers -> d_out[2]
__global__ __launch_bounds__(256) void k_tail(const float* __restrict__ mp,
                                              const float* __restrict__ words,
                                              const float* __restrict__ fcW,
                                              const float* __restrict__ fcb,
                                              const float* __restrict__ oW,
                                              const float* __restrict__ ob,
                                              const float* __restrict__ iW,
                                              const float* __restrict__ ib,
                                              float* __restrict__ out) {
  __shared__ float cat[128];
  __shared__ float mred[4][64];
  int t = threadIdx.x;
  if (t < 64) {
    float s = 0.f;
    for (int w = 0; w < 64; ++w) s += mp[w * 64 + t];
    cat[t] = s * (1.0f / N_ATOM);
  }
  {
    int ch = t >> 6, d = t & 63;
    float s = 0.f;
    for (int q = 0; q < 256; ++q) {
      int k = ch * 256 + q;
      s = fmaf(words[k], fcW[(size_t)k * 64 + d], s);
    }
    mred[ch][d] = s;
  }
  __syncthreads();
  if (t < 64) cat[64 + t] = mred[0][t] + mred[1][t] + mred[2][t] + mred[3][t] + fcb[t];
  __syncthreads();
  for (int j = 0; j < 2; ++j) {
    float s = 0.f;
    if (t < 128) {
      s = ob[j * 128 + t];
      for (int k = 0; k < 128; ++k)
        s = fmaf(cat[k], oW[(size_t)j * 128 * 128 + k * 128 + t], s);
      s = fmaxf(s, 0.f);
    }
    __syncthreads();
    if (t < 128) cat[t] = s;
    __syncthreads();
  }
  if (t < 2) {
    float s = ib[t];
    for (int k = 0; k < 128; ++k) s = fmaf(cat[k], iW[k * 2 + t], s);
    out[t] = s;
  }
}

// ---------------------------------------------------------------------------
extern "C" void kernel_launch(void* const* d_in, const int* in_sizes, int n_in,
                              void* d_out, int out_size, void* d_ws, size_t ws_size,
                              hipStream_t stream) {
  const int*   fp    = (const int*)  d_in[0];
  const int*   adl   = (const int*)  d_in[1];
  const float* bfeat = (const float*)d_in[2];
  const int*   bdl   = (const int*)  d_in[3];
  const int*   ibj   = (const int*)  d_in[4];
  const float* adj   = (const float*)d_in[5];
  const float* words = (const float*)d_in[6];
  const float* emb   = (const float*)d_in[7];
  const float* bW    = (const float*)d_in[8];
  const float* bb    = (const float*)d_in[9];
  const float* subW  = (const float*)d_in[10];
  const float* subb  = (const float*)d_in[11];
  const float* nW    = (const float*)d_in[12];
  const float* nb    = (const float*)d_in[13];
  const float* sW    = (const float*)d_in[14];
  const float* sb    = (const float*)d_in[15];
  const float* fcW   = (const float*)d_in[16];
  const float* fcb   = (const float*)d_in[17];
  const float* oW    = (const float*)d_in[18];
  const float* ob    = (const float*)d_in[19];
  const float* iW    = (const float*)d_in[20];
  const float* ib    = (const float*)d_in[21];
  float* out = (float*)d_out;

  char* ws = (char*)d_ws;
  const size_t MB = 1ull << 20;
  float*          x      = (float*)(ws + 0 * MB);    // 2 MB
  float*          atom_f = (float*)(ws + 2 * MB);    // 2 MB
  float*          A      = (float*)(ws + 4 * MB);    // 2 MB
  unsigned short* hsT    = (unsigned short*)(ws + 6 * MB);  // 1 MB
  float*          mp     = (float*)(ws + 7 * MB);    // 16 KB
  float*          bond_f = (float*)(ws + 8 * MB);    // 16 MB
  float*          B      = (float*)(ws + 24 * MB);   // 16 MB
  float*          part   = (float*)(ws + 40 * MB);   // 16 MB (ADJ_S slices)

  // bond_f (independent of sub_graph)
  k_bondf<<<N_EDGE / 16, 256, 0, stream>>>(bfeat, bW, bb, bond_f);

  // sub_graph: fused embed+hs0, MFMA adj GEMM, fused red+hs1, GEMM, final red
  k_pre_hs<<<512, 256, 0, stream>>>(0, fp, emb, part, x, subW, subb, hsT);
  {
    dim3 g(N_ATOM / BM, ADJ_S);
    k_adjmm<<<g, 256, 0, stream>>>(adj, hsT, part);
    k_pre_hs<<<512, 256, 0, stream>>>(1, fp, emb, part, x, subW + 64 * 64,
                                      subb + 64, hsT);
    k_adjmm<<<g, 256, 0, stream>>>(adj, hsT, part);
    k_red_final<<<512, 256, 0, stream>>>(x, atom_f, part);
  }

  // GNN
  for (int i = 0; i < 3; ++i) {
    k_AB<<<N_ATOM / 16 + N_EDGE / 16, 256, 0, stream>>>(
        atom_f, bond_f, nW + i * 128 * 64, nb + i * 64, A, B);
    k_upd<<<N_ATOM / 16, 256, 0, stream>>>(adl, bdl, A, B, atom_f);
    k_side<<<N_EDGE / 16, 256, 0, stream>>>(ibj, atom_f, sW + i * 64 * 64,
                                            sb + i * 64, bond_f);
  }

  // tail
  k_meanpart<<<64, 256, 0, stream>>>(x, atom_f, mp);
  k_tail<<<1, 256, 0, stream>>>(mp, words, fcW, fcb, oW, ob, iW, ib, out);
}